// Round 1
// baseline (2848.185 us; speedup 1.0000x reference)
//
#include <hip/hip_runtime.h>

#define D 128

// ---------------------------------------------------------------------------
// Kernel 1: H[n][o] = sum_d emb[n][d] * W[o][d]   (h = E @ W^T)
// W transposed into LDS (Wt[d][o]); each wave handles 8 nodes, each lane
// computes outputs {l, l+64} for those 8 nodes -> 16 FMA per d-iteration.
// ---------------------------------------------------------------------------
__global__ __launch_bounds__(256) void gemm_h_kernel(
    const float* __restrict__ emb, const float* __restrict__ W,
    float* __restrict__ H, int n_nodes) {
  __shared__ float Wt[D * D];       // Wt[d*128 + o] = W[o*128 + d]  (64 KB)
  __shared__ float erow[4][8 * D];  // per-wave staging of 8 node rows (16 KB)

  const int tid = threadIdx.x;
  for (int i = tid; i < D * D; i += 256) {
    int o = i >> 7;
    int d = i & (D - 1);
    Wt[d * D + o] = W[i];
  }
  __syncthreads();

  const int w = tid >> 6;  // wave 0..3
  const int l = tid & 63;  // lane
  int base = blockIdx.x * 32 + w * 8;
  if (base >= n_nodes) return;

  int nrows = min(8, n_nodes - base);
  // 8 node rows are 1024 contiguous floats: coalesced float4 stage into LDS.
  const float4* src = (const float4*)(emb + (size_t)base * D);
  float4* dst = (float4*)erow[w];
  int nf4 = nrows * (D / 4);
  for (int i = l; i < nf4; i += 64) dst[i] = src[i];
  // Each wave reads only its own erow slice; compiler inserts lgkmcnt waits.

  float acc[8][2];
#pragma unroll
  for (int j = 0; j < 8; ++j) {
    acc[j][0] = 0.f;
    acc[j][1] = 0.f;
  }

  for (int d = 0; d < D; ++d) {
    float w0 = Wt[d * D + l];        // lanes consecutive -> conflict-free
    float w1 = Wt[d * D + 64 + l];
#pragma unroll
    for (int j = 0; j < 8; ++j) {
      float ed = erow[w][j * D + d];  // broadcast (same addr all lanes)
      acc[j][0] = fmaf(ed, w0, acc[j][0]);
      acc[j][1] = fmaf(ed, w1, acc[j][1]);
    }
  }

  for (int j = 0; j < nrows; ++j) {
    size_t n = (size_t)(base + j);
    H[n * D + l]      = acc[j][0];
    H[n * D + 64 + l] = acc[j][1];
  }
}

// ---------------------------------------------------------------------------
// Kernel 2: edge scatter. 32 lanes per edge; each lane float4-gathers h[col]
// and does 4 fp32 atomicAdds into out[row].
// ---------------------------------------------------------------------------
__global__ __launch_bounds__(256) void spmm_scatter_kernel(
    const float* __restrict__ H, const int* __restrict__ rows,
    const int* __restrict__ cols, const float* __restrict__ vals,
    float* __restrict__ out, int E) {
  long long gid = (long long)blockIdx.x * blockDim.x + threadIdx.x;
  int e = (int)(gid >> 5);
  int l = (int)(gid & 31);
  if (e >= E) return;

  int r = rows[e];
  int c = cols[e];
  float v = vals[e];

  float4 h4 = ((const float4*)(H + (size_t)c * D))[l];
  float* op = out + (size_t)r * D + l * 4;
  atomicAdd(op + 0, v * h4.x);
  atomicAdd(op + 1, v * h4.y);
  atomicAdd(op + 2, v * h4.z);
  atomicAdd(op + 3, v * h4.w);
}

// ---------------------------------------------------------------------------
// Kernel 3: in-place leaky relu (slope 0.2), float4 grid-stride.
// ---------------------------------------------------------------------------
__global__ __launch_bounds__(256) void leaky_kernel(float* __restrict__ out,
                                                    int n4) {
  for (int i = blockIdx.x * blockDim.x + threadIdx.x; i < n4;
       i += gridDim.x * blockDim.x) {
    float4 v = ((const float4*)out)[i];
    v.x = v.x >= 0.f ? v.x : 0.2f * v.x;
    v.y = v.y >= 0.f ? v.y : 0.2f * v.y;
    v.z = v.z >= 0.f ? v.z : 0.2f * v.z;
    v.w = v.w >= 0.f ? v.w : 0.2f * v.w;
    ((float4*)out)[i] = v;
  }
}

extern "C" void kernel_launch(void* const* d_in, const int* in_sizes, int n_in,
                              void* d_out, int out_size, void* d_ws,
                              size_t ws_size, hipStream_t stream) {
  const float* emb  = (const float*)d_in[0];
  const float* W    = (const float*)d_in[1];
  const int*   rows = (const int*)d_in[2];
  const int*   cols = (const int*)d_in[3];
  const float* vals = (const float*)d_in[4];
  float* out = (float*)d_out;
  float* H   = (float*)d_ws;  // 100000*128*4 = 51.2 MB scratch

  int n_nodes = in_sizes[0] / D;
  int E = in_sizes[2];

  // out accumulates via atomics -> must start at zero every call.
  hipMemsetAsync(d_out, 0, (size_t)n_nodes * D * sizeof(float), stream);

  int gblocks = (n_nodes + 31) / 32;
  gemm_h_kernel<<<gblocks, 256, 0, stream>>>(emb, W, H, n_nodes);

  long long sthreads = (long long)E * 32;
  int sblocks = (int)((sthreads + 255) / 256);
  spmm_scatter_kernel<<<sblocks, 256, 0, stream>>>(H, rows, cols, vals, out, E);

  int n4 = n_nodes * D / 4;
  leaky_kernel<<<1024, 256, 0, stream>>>(out, n4);
}

// Round 2
// 503.825 us; speedup vs baseline: 5.6531x; 5.6531x over previous
//
#include <hip/hip_runtime.h>

#define D 128

// ---------------------------------------------------------------------------
// Kernel 1: H[n][o] = sum_d emb[n][d] * W[o][d]   (h = E @ W^T)
// ---------------------------------------------------------------------------
__global__ __launch_bounds__(256) void gemm_h_kernel(
    const float* __restrict__ emb, const float* __restrict__ W,
    float* __restrict__ H, int n_nodes) {
  __shared__ float Wt[D * D];       // Wt[d*128 + o] = W[o*128 + d]  (64 KB)
  __shared__ float erow[4][8 * D];  // per-wave staging of 8 node rows (16 KB)

  const int tid = threadIdx.x;
  for (int i = tid; i < D * D; i += 256) {
    int o = i >> 7;
    int d = i & (D - 1);
    Wt[d * D + o] = W[i];
  }
  __syncthreads();

  const int w = tid >> 6;
  const int l = tid & 63;
  int base = blockIdx.x * 32 + w * 8;
  if (base >= n_nodes) return;

  int nrows = min(8, n_nodes - base);
  const float4* src = (const float4*)(emb + (size_t)base * D);
  float4* dst = (float4*)erow[w];
  int nf4 = nrows * (D / 4);
  for (int i = l; i < nf4; i += 64) dst[i] = src[i];

  float acc[8][2];
#pragma unroll
  for (int j = 0; j < 8; ++j) { acc[j][0] = 0.f; acc[j][1] = 0.f; }

  for (int d = 0; d < D; ++d) {
    float w0 = Wt[d * D + l];
    float w1 = Wt[d * D + 64 + l];
#pragma unroll
    for (int j = 0; j < 8; ++j) {
      float ed = erow[w][j * D + d];
      acc[j][0] = fmaf(ed, w0, acc[j][0]);
      acc[j][1] = fmaf(ed, w1, acc[j][1]);
    }
  }

  for (int j = 0; j < nrows; ++j) {
    size_t n = (size_t)(base + j);
    H[n * D + l]      = acc[j][0];
    H[n * D + 64 + l] = acc[j][1];
  }
}

// ---------------------------------------------------------------------------
// CSR build: histogram -> 2-level exclusive scan -> bucket scatter.
// ---------------------------------------------------------------------------
__global__ __launch_bounds__(256) void hist_kernel(const int* __restrict__ rows,
                                                   int* __restrict__ deg, int E) {
  int e = blockIdx.x * 256 + threadIdx.x;
  if (e < E) atomicAdd(&deg[rows[e]], 1);
}

// Block-local exclusive scan (256 items/block) + per-block totals.
__global__ __launch_bounds__(256) void scan_blocks_kernel(
    const int* __restrict__ deg, int* __restrict__ ofs,
    int* __restrict__ partials, int n) {
  __shared__ int s[256];
  int t = threadIdx.x;
  int i = blockIdx.x * 256 + t;
  int v = (i < n) ? deg[i] : 0;
  s[t] = v;
  __syncthreads();
  for (int d = 1; d < 256; d <<= 1) {
    int x = (t >= d) ? s[t - d] : 0;
    __syncthreads();
    s[t] += x;
    __syncthreads();
  }
  if (i < n) ofs[i] = s[t] - v;  // exclusive
  if (t == 255) partials[blockIdx.x] = s[255];
}

// Single-block exclusive scan of block totals (nb <= 1024).
__global__ __launch_bounds__(1024) void scan_partials_kernel(
    int* __restrict__ partials, int nb) {
  __shared__ int s[1024];
  int t = threadIdx.x;
  int v = (t < nb) ? partials[t] : 0;
  s[t] = v;
  __syncthreads();
  for (int d = 1; d < 1024; d <<= 1) {
    int x = (t >= d) ? s[t - d] : 0;
    __syncthreads();
    s[t] += x;
    __syncthreads();
  }
  if (t < nb) partials[t] = s[t] - v;  // exclusive
}

__global__ __launch_bounds__(256) void scan_add_kernel(
    int* __restrict__ ofs, int* __restrict__ cursor,
    const int* __restrict__ partials, int n) {
  int i = blockIdx.x * 256 + threadIdx.x;
  if (i < n) {
    int o = ofs[i] + partials[blockIdx.x];
    ofs[i] = o;
    cursor[i] = o;
  }
}

__global__ __launch_bounds__(256) void bucket_kernel(
    const int* __restrict__ rows, const int* __restrict__ cols,
    const float* __restrict__ vals, int* __restrict__ cursor,
    int* __restrict__ ccol, float* __restrict__ cval, int E) {
  int e = blockIdx.x * 256 + threadIdx.x;
  if (e >= E) return;
  int r = rows[e];
  int pos = atomicAdd(&cursor[r], 1);
  ccol[pos] = cols[e];
  cval[pos] = vals[e];
}

// ---------------------------------------------------------------------------
// Row gather: one wave per row. Lane l accumulates out[r][l], out[r][64+l]
// in registers; fused leaky-relu on store. Zero fp32 atomics.
// ---------------------------------------------------------------------------
__global__ __launch_bounds__(256) void row_gather_kernel(
    const float* __restrict__ H, const int* __restrict__ ofs,
    const int* __restrict__ ccol, const float* __restrict__ cval,
    float* __restrict__ out, int n, int E) {
  int w = (blockIdx.x * 256 + threadIdx.x) >> 6;  // row id
  int l = threadIdx.x & 63;
  if (w >= n) return;
  int s = ofs[w];
  int e = (w + 1 < n) ? ofs[w + 1] : E;

  float a0 = 0.f, a1 = 0.f;
  for (int j = s; j < e; ++j) {
    int c = ccol[j];          // wave-uniform
    float v = cval[j];
    a0 = fmaf(v, H[(size_t)c * D + l], a0);
    a1 = fmaf(v, H[(size_t)c * D + 64 + l], a1);
  }
  a0 = a0 >= 0.f ? a0 : 0.2f * a0;
  a1 = a1 >= 0.f ? a1 : 0.2f * a1;
  out[(size_t)w * D + l]      = a0;
  out[(size_t)w * D + 64 + l] = a1;
}

// ---------------------------------------------------------------------------
// Fallback path (atomics) in case ws_size is too small for CSR scratch.
// ---------------------------------------------------------------------------
__global__ __launch_bounds__(256) void spmm_scatter_kernel(
    const float* __restrict__ H, const int* __restrict__ rows,
    const int* __restrict__ cols, const float* __restrict__ vals,
    float* __restrict__ out, int E) {
  long long gid = (long long)blockIdx.x * blockDim.x + threadIdx.x;
  int e = (int)(gid >> 5);
  int l = (int)(gid & 31);
  if (e >= E) return;
  int r = rows[e];
  int c = cols[e];
  float v = vals[e];
  float4 h4 = ((const float4*)(H + (size_t)c * D))[l];
  float* op = out + (size_t)r * D + l * 4;
  atomicAdd(op + 0, v * h4.x);
  atomicAdd(op + 1, v * h4.y);
  atomicAdd(op + 2, v * h4.z);
  atomicAdd(op + 3, v * h4.w);
}

__global__ __launch_bounds__(256) void leaky_kernel(float* __restrict__ out,
                                                    int n4) {
  for (int i = blockIdx.x * blockDim.x + threadIdx.x; i < n4;
       i += gridDim.x * blockDim.x) {
    float4 v = ((const float4*)out)[i];
    v.x = v.x >= 0.f ? v.x : 0.2f * v.x;
    v.y = v.y >= 0.f ? v.y : 0.2f * v.y;
    v.z = v.z >= 0.f ? v.z : 0.2f * v.z;
    v.w = v.w >= 0.f ? v.w : 0.2f * v.w;
    ((float4*)out)[i] = v;
  }
}

extern "C" void kernel_launch(void* const* d_in, const int* in_sizes, int n_in,
                              void* d_out, int out_size, void* d_ws,
                              size_t ws_size, hipStream_t stream) {
  const float* emb  = (const float*)d_in[0];
  const float* W    = (const float*)d_in[1];
  const int*   rows = (const int*)d_in[2];
  const int*   cols = (const int*)d_in[3];
  const float* vals = (const float*)d_in[4];
  float* out = (float*)d_out;

  int N = in_sizes[0] / D;
  int E = in_sizes[2];

  // Workspace carve-out (256B-aligned chunks).
  char* p = (char*)d_ws;
  auto carve = [&](size_t bytes) {
    char* r = p;
    p += (bytes + 255) & ~(size_t)255;
    return r;
  };
  float* H        = (float*)carve((size_t)N * D * sizeof(float));
  int*   deg      = (int*)carve((size_t)N * sizeof(int));
  int*   ofs      = (int*)carve((size_t)(N + 1) * sizeof(int));
  int*   cursor   = (int*)carve((size_t)N * sizeof(int));
  int*   ccol     = (int*)carve((size_t)E * sizeof(int));
  float* cval     = (float*)carve((size_t)E * sizeof(float));
  int*   partials = (int*)carve(4096 * sizeof(int));
  size_t needed = (size_t)(p - (char*)d_ws);

  int gblocks = (N + 31) / 32;
  gemm_h_kernel<<<gblocks, 256, 0, stream>>>(emb, W, H, N);

  int nb_scan = (N + 255) / 256;
  int eb = (E + 255) / 256;

  if (needed <= ws_size && nb_scan <= 1024) {
    // CSR path — no fp32 atomics.
    hipMemsetAsync(deg, 0, (size_t)N * sizeof(int), stream);
    hist_kernel<<<eb, 256, 0, stream>>>(rows, deg, E);
    scan_blocks_kernel<<<nb_scan, 256, 0, stream>>>(deg, ofs, partials, N);
    scan_partials_kernel<<<1, 1024, 0, stream>>>(partials, nb_scan);
    scan_add_kernel<<<nb_scan, 256, 0, stream>>>(ofs, cursor, partials, N);
    bucket_kernel<<<eb, 256, 0, stream>>>(rows, cols, vals, cursor, ccol, cval, E);
    int rb = (N * 64 + 255) / 256;  // one wave per row
    row_gather_kernel<<<rb, 256, 0, stream>>>(H, ofs, ccol, cval, out, N, E);
  } else {
    // Fallback: atomic scatter.
    hipMemsetAsync(d_out, 0, (size_t)N * D * sizeof(float), stream);
    long long sthreads = (long long)E * 32;
    int sblocks = (int)((sthreads + 255) / 256);
    spmm_scatter_kernel<<<sblocks, 256, 0, stream>>>(H, rows, cols, vals, out, E);
    leaky_kernel<<<1024, 256, 0, stream>>>(out, N * D / 4);
  }
}

// Round 3
// 328.690 us; speedup vs baseline: 8.6653x; 1.5328x over previous
//
#include <hip/hip_runtime.h>
#include <hip/hip_bf16.h>

#define D 128

typedef __attribute__((ext_vector_type(8))) short short8;
typedef __attribute__((ext_vector_type(4))) float f32x4;

__device__ __forceinline__ short f2bf(float f) {
  __hip_bfloat16 h = __float2bfloat16(f);
  return (short)*reinterpret_cast<unsigned short*>(&h);
}

// ---------------------------------------------------------------------------
// GEMM via MFMA bf16: H[n][o] = sum_d emb[n][d] * W[o][d].
// Block = 256 thr = 4 waves; each wave one 16-row tile; BM=64/block.
// W cast to bf16 in LDS (32 KB), XOR-swizzled for conflict-free ds_read_b128.
// A fragments loaded directly from global (lane reads its row's 32B/k-step).
// Fragment layouts (16x16x32): A[row=lane&15][k=(lane>>4)*8+i],
// B[k=(lane>>4)*8+i][col=lane&15], D[row=(lane>>4)*4+r][col=lane&15].
// ---------------------------------------------------------------------------
__global__ __launch_bounds__(256) void gemm_mfma_kernel(
    const float* __restrict__ emb, const float* __restrict__ W,
    float* __restrict__ H, int N) {
  __shared__ short8 WldsV[2048];  // 128 rows x 256B (128 bf16), 32 KB
  char* Wlds = (char*)WldsV;
  const int tid = threadIdx.x;

  // Stage W -> bf16 LDS, swizzle 16B block index with (o&7).
  for (int i = tid; i < 128 * 16; i += 256) {
    int o = i >> 4, dblk = i & 15;
    const float* wp = W + o * D + dblk * 8;
    float4 f0 = *(const float4*)wp;
    float4 f1 = *(const float4*)(wp + 4);
    short8 u;
    u[0] = f2bf(f0.x); u[1] = f2bf(f0.y); u[2] = f2bf(f0.z); u[3] = f2bf(f0.w);
    u[4] = f2bf(f1.x); u[5] = f2bf(f1.y); u[6] = f2bf(f1.z); u[7] = f2bf(f1.w);
    *(short8*)(Wlds + o * 256 + ((dblk ^ (o & 7)) << 4)) = u;
  }
  __syncthreads();

  const int w = tid >> 6, l = tid & 63;
  const int lo = l & 15, hi = l >> 4;
  const int mbase = blockIdx.x * 64 + w * 16;

  int arow = mbase + lo;
  if (arow >= N) arow = N - 1;  // clamp; stores are guarded
  const float* ap = emb + (size_t)arow * D + hi * 8;

  float4 a0[4], a1[4];
#pragma unroll
  for (int kb = 0; kb < 4; ++kb) {
    a0[kb] = *(const float4*)(ap + kb * 32);
    a1[kb] = *(const float4*)(ap + kb * 32 + 4);
  }

  f32x4 acc[8];
#pragma unroll
  for (int ot = 0; ot < 8; ++ot) acc[ot] = (f32x4){0.f, 0.f, 0.f, 0.f};

  const char* brow = Wlds + lo * 256;  // o = ot*16 + lo; o&7 == l&7
#pragma unroll
  for (int kb = 0; kb < 4; ++kb) {
    short8 a;
    a[0] = f2bf(a0[kb].x); a[1] = f2bf(a0[kb].y);
    a[2] = f2bf(a0[kb].z); a[3] = f2bf(a0[kb].w);
    a[4] = f2bf(a1[kb].x); a[5] = f2bf(a1[kb].y);
    a[6] = f2bf(a1[kb].z); a[7] = f2bf(a1[kb].w);
    const int xb = (((kb << 2) | hi) ^ (l & 7)) << 4;
#pragma unroll
    for (int ot = 0; ot < 8; ++ot) {
      short8 b = *(const short8*)(brow + ot * 4096 + xb);
      acc[ot] = __builtin_amdgcn_mfma_f32_16x16x32_bf16(a, b, acc[ot], 0, 0, 0);
    }
  }

  const int rowout = mbase + hi * 4;
#pragma unroll
  for (int r = 0; r < 4; ++r) {
    int ro = rowout + r;
    if (ro < N) {
      float* op = H + (size_t)ro * D + lo;
#pragma unroll
      for (int ot = 0; ot < 8; ++ot) op[ot * 16] = acc[ot][r];
    }
  }
}

// ---------------------------------------------------------------------------
// CSR build: histogram -> 2-level exclusive scan -> bucket scatter (packed).
// ---------------------------------------------------------------------------
__global__ __launch_bounds__(256) void hist_kernel(const int* __restrict__ rows,
                                                   int* __restrict__ deg, int E) {
  int e = blockIdx.x * 256 + threadIdx.x;
  if (e < E) atomicAdd(&deg[rows[e]], 1);
}

__global__ __launch_bounds__(256) void scan_blocks_kernel(
    const int* __restrict__ deg, int* __restrict__ ofs,
    int* __restrict__ partials, int n) {
  __shared__ int s[256];
  int t = threadIdx.x;
  int i = blockIdx.x * 256 + t;
  int v = (i < n) ? deg[i] : 0;
  s[t] = v;
  __syncthreads();
  for (int d = 1; d < 256; d <<= 1) {
    int x = (t >= d) ? s[t - d] : 0;
    __syncthreads();
    s[t] += x;
    __syncthreads();
  }
  if (i < n) ofs[i] = s[t] - v;
  if (t == 255) partials[blockIdx.x] = s[255];
}

__global__ __launch_bounds__(1024) void scan_partials_kernel(
    int* __restrict__ partials, int nb) {
  __shared__ int s[1024];
  int t = threadIdx.x;
  int v = (t < nb) ? partials[t] : 0;
  s[t] = v;
  __syncthreads();
  for (int d = 1; d < 1024; d <<= 1) {
    int x = (t >= d) ? s[t - d] : 0;
    __syncthreads();
    s[t] += x;
    __syncthreads();
  }
  if (t < nb) partials[t] = s[t] - v;
}

__global__ __launch_bounds__(256) void scan_add_kernel(
    int* __restrict__ ofs, int* __restrict__ cursor,
    const int* __restrict__ partials, int n) {
  int i = blockIdx.x * 256 + threadIdx.x;
  if (i < n) {
    int o = ofs[i] + partials[blockIdx.x];
    ofs[i] = o;
    cursor[i] = o;
  }
}

__global__ __launch_bounds__(256) void bucket_kernel(
    const int* __restrict__ rows, const int* __restrict__ cols,
    const float* __restrict__ vals, int* __restrict__ cursor,
    float2* __restrict__ cent, int E) {
  int e = blockIdx.x * 256 + threadIdx.x;
  if (e >= E) return;
  int r = rows[e];
  int pos = atomicAdd(&cursor[r], 1);
  float2 m;
  m.x = __int_as_float(cols[e]);
  m.y = vals[e];
  cent[pos] = m;  // one 8B store
}

// ---------------------------------------------------------------------------
// Row gather: one wave per row, lane = float2 of the 128-wide output.
// One dwordx2 load per edge (512B/wave = exactly one H row), 4-edge unroll.
// ---------------------------------------------------------------------------
__global__ __launch_bounds__(256) void row_gather_kernel(
    const float* __restrict__ H, const int* __restrict__ ofs,
    const float2* __restrict__ cent, float* __restrict__ out, int n, int E) {
  int w = (blockIdx.x * 256 + threadIdx.x) >> 6;
  int l = threadIdx.x & 63;
  if (w >= n) return;
  int s = ofs[w];
  int e2 = (w + 1 < n) ? ofs[w + 1] : E;

  float ax = 0.f, ay = 0.f;
  int j = s;
  for (; j + 4 <= e2; j += 4) {
    float2 m0 = cent[j];
    float2 m1 = cent[j + 1];
    float2 m2 = cent[j + 2];
    float2 m3 = cent[j + 3];
    const float2* h0 = (const float2*)(H + (size_t)__float_as_int(m0.x) * D);
    const float2* h1 = (const float2*)(H + (size_t)__float_as_int(m1.x) * D);
    const float2* h2 = (const float2*)(H + (size_t)__float_as_int(m2.x) * D);
    const float2* h3 = (const float2*)(H + (size_t)__float_as_int(m3.x) * D);
    float2 x0 = h0[l];
    float2 x1 = h1[l];
    float2 x2 = h2[l];
    float2 x3 = h3[l];
    ax = fmaf(m0.y, x0.x, ax); ay = fmaf(m0.y, x0.y, ay);
    ax = fmaf(m1.y, x1.x, ax); ay = fmaf(m1.y, x1.y, ay);
    ax = fmaf(m2.y, x2.x, ax); ay = fmaf(m2.y, x2.y, ay);
    ax = fmaf(m3.y, x3.x, ax); ay = fmaf(m3.y, x3.y, ay);
  }
  for (; j < e2; ++j) {
    float2 m = cent[j];
    const float2* h = (const float2*)(H + (size_t)__float_as_int(m.x) * D);
    float2 x = h[l];
    ax = fmaf(m.y, x.x, ax); ay = fmaf(m.y, x.y, ay);
  }
  ax = ax >= 0.f ? ax : 0.2f * ax;
  ay = ay >= 0.f ? ay : 0.2f * ay;
  float2 o;
  o.x = ax;
  o.y = ay;
  ((float2*)(out + (size_t)w * D))[l] = o;
}

// ---------------------------------------------------------------------------
// Fallback (atomics) if ws too small.
// ---------------------------------------------------------------------------
__global__ __launch_bounds__(256) void spmm_scatter_kernel(
    const float* __restrict__ H, const int* __restrict__ rows,
    const int* __restrict__ cols, const float* __restrict__ vals,
    float* __restrict__ out, int E) {
  long long gid = (long long)blockIdx.x * blockDim.x + threadIdx.x;
  int e = (int)(gid >> 5);
  int l = (int)(gid & 31);
  if (e >= E) return;
  int r = rows[e];
  int c = cols[e];
  float v = vals[e];
  float4 h4 = ((const float4*)(H + (size_t)c * D))[l];
  float* op = out + (size_t)r * D + l * 4;
  atomicAdd(op + 0, v * h4.x);
  atomicAdd(op + 1, v * h4.y);
  atomicAdd(op + 2, v * h4.z);
  atomicAdd(op + 3, v * h4.w);
}

__global__ __launch_bounds__(256) void leaky_kernel(float* __restrict__ out,
                                                    int n4) {
  for (int i = blockIdx.x * blockDim.x + threadIdx.x; i < n4;
       i += gridDim.x * blockDim.x) {
    float4 v = ((const float4*)out)[i];
    v.x = v.x >= 0.f ? v.x : 0.2f * v.x;
    v.y = v.y >= 0.f ? v.y : 0.2f * v.y;
    v.z = v.z >= 0.f ? v.z : 0.2f * v.z;
    v.w = v.w >= 0.f ? v.w : 0.2f * v.w;
    ((float4*)out)[i] = v;
  }
}

extern "C" void kernel_launch(void* const* d_in, const int* in_sizes, int n_in,
                              void* d_out, int out_size, void* d_ws,
                              size_t ws_size, hipStream_t stream) {
  const float* emb  = (const float*)d_in[0];
  const float* W    = (const float*)d_in[1];
  const int*   rows = (const int*)d_in[2];
  const int*   cols = (const int*)d_in[3];
  const float* vals = (const float*)d_in[4];
  float* out = (float*)d_out;

  int N = in_sizes[0] / D;
  int E = in_sizes[2];

  char* p = (char*)d_ws;
  auto carve = [&](size_t bytes) {
    char* r = p;
    p += (bytes + 255) & ~(size_t)255;
    return r;
  };
  float*  H        = (float*)carve((size_t)N * D * sizeof(float));
  int*    deg      = (int*)carve((size_t)N * sizeof(int));
  int*    ofs      = (int*)carve((size_t)(N + 1) * sizeof(int));
  int*    cursor   = (int*)carve((size_t)N * sizeof(int));
  float2* cent     = (float2*)carve((size_t)E * sizeof(float2));
  int*    partials = (int*)carve(4096 * sizeof(int));
  size_t needed = (size_t)(p - (char*)d_ws);

  int gblocks = (N + 63) / 64;
  gemm_mfma_kernel<<<gblocks, 256, 0, stream>>>(emb, W, H, N);

  int nb_scan = (N + 255) / 256;
  int eb = (E + 255) / 256;

  if (needed <= ws_size && nb_scan <= 1024) {
    hipMemsetAsync(deg, 0, (size_t)N * sizeof(int), stream);
    hist_kernel<<<eb, 256, 0, stream>>>(rows, deg, E);
    scan_blocks_kernel<<<nb_scan, 256, 0, stream>>>(deg, ofs, partials, N);
    scan_partials_kernel<<<1, 1024, 0, stream>>>(partials, nb_scan);
    scan_add_kernel<<<nb_scan, 256, 0, stream>>>(ofs, cursor, partials, N);
    bucket_kernel<<<eb, 256, 0, stream>>>(rows, cols, vals, cursor, cent, E);
    int rb = (N * 64 + 255) / 256;
    row_gather_kernel<<<rb, 256, 0, stream>>>(H, ofs, cent, out, N, E);
  } else {
    hipMemsetAsync(d_out, 0, (size_t)N * D * sizeof(float), stream);
    long long sthreads = (long long)E * 32;
    int sblocks = (int)((sthreads + 255) / 256);
    spmm_scatter_kernel<<<sblocks, 256, 0, stream>>>(H, rows, cols, vals, out, E);
    leaky_kernel<<<1024, 256, 0, stream>>>(out, N * D / 4);
  }
}